// Round 11
// baseline (4106.755 us; speedup 1.0000x reference)
//
#include <hip/hip_runtime.h>
#include <math.h>
#include <stdint.h>

// ReLSTM_18940805775611 — B=512, T=128, H=512, 2-layer LSTM, 128 TF + 127 AR.
// R25 (3076us) -> R29 (3030us): persistent, ITER fusion, MALL-scope flag sync,
// AR restructure. Calibration from R29's marginal gain: per-RT cost under load
// is ~1.2-1.5us (not 0.4) because ALL h loads are sc0sc1 MALL-bypass:
// 256 blocks x 128KB = 33.5MB/step uncached through the coherency point
// (32x cross-block redundancy of the group all-to-all) -> queueing inflates
// every protocol op. R30: decontend via CACHED h reads + acquire fence.
//  - h/parts loads: plain cacheable global_load_dwordx4 (inline asm, no sc
//    bits -> vmcnt ladders unchanged). 4 same-group blocks per XCD share L2
//    fills -> MALL reads drop up to 4x; residual RTs speed up as queues drain.
//  - Visibility: after each flag poll, __builtin_amdgcn_fence(ACQUIRE,
//    "agent") -> buffer_inv drops clean L2 lines, so cached loads cannot see
//    stale h. Producers keep sc0sc1 write-through stores (no dirty lines);
//    flags stay sc0sc1. This is the ROCm release/acquire pattern.
//  - R18's fence disaster does NOT apply: weights are LDS/VGPR-resident now;
//    the only invalidated state is exactly the h-data we want refetched.
//    Canary: FETCH_SIZE must stay ~1.0-1.2e6 KB (explosion => revert).
//  - Everything else byte-identical to R29 (protocol, ladders, bounded polls).

namespace {
constexpr int NH  = 512;    // hidden
constexpr int NT  = 128;    // seq len
constexpr int NB  = 512;    // batch
}

typedef __attribute__((ext_vector_type(8))) short bf16x8;
typedef __attribute__((ext_vector_type(4))) float f32x4;
typedef __attribute__((ext_vector_type(4))) unsigned int u32x4;

// Present in case the harness resolves this symbol.
__global__ void ReLSTM_18940805775611_kernel() {}

__device__ __forceinline__ unsigned short lstm9_f2b(float f) {
    union { float f; uint32_t i; } v; v.f = f;
    const uint32_t r = v.i + 0x7FFFu + ((v.i >> 16) & 1u);   // RNE
    return (unsigned short)(r >> 16);
}
__device__ __forceinline__ float lstm9_sig(float x) {
    return 1.0f / (1.0f + expf(-x));
}

// ---- sentinel: truncation diagnostic ----
__global__ void lstm9_mark(float* out) {
    const int i = blockIdx.x * blockDim.x + threadIdx.x;
    if (i < NB * NT) out[i] = 2.03125f;
}

// ---- one-time prep (re-run every launch -> graph-replay safe) ----
__global__ void lstm9_prep(
    const float* whh0, const float* wih1, const float* whh1,
    const float* bih0, const float* bhh0, const float* bih1, const float* bhh1,
    unsigned short* wb0, unsigned short* wb1i, unsigned short* wb1h,
    float* bsum0, float* bsum1,
    unsigned short* hz, int* flags)
{
    const size_t stride = (size_t)gridDim.x * blockDim.x;
    const size_t i0 = (size_t)blockIdx.x * blockDim.x + threadIdx.x;
    const size_t NW = (size_t)4 * NH * NH;
    for (size_t i = i0; i < NW; i += stride) {
        wb0 [i] = lstm9_f2b(whh0[i]);
        wb1i[i] = lstm9_f2b(wih1[i]);
        wb1h[i] = lstm9_f2b(whh1[i]);
    }
    for (size_t i = i0; i < (size_t)4 * NH; i += stride) {
        bsum0[i] = bih0[i] + bhh0[i];
        bsum1[i] = bih1[i] + bhh1[i];
    }
    for (size_t i = i0; i < (size_t)4 * NB * NH; i += stride) hz[i] = 0;
    for (size_t i = i0; i < (size_t)2 * 256 * 8 * 32; i += stride) flags[i] = 0;
}

// ---- memory helpers ----
// cacheable load (h/parts data; correctness via acquire fence after poll)
__device__ __forceinline__ void lstm9_ldC(u32x4& d, const void* p) {
    asm volatile("global_load_dwordx4 %0, %1, off"
                 : "=v"(d) : "v"(p) : "memory");
}
#define LSTM9_W8(N, a,b,c,d,e,f,g,h) \
    asm volatile("s_waitcnt vmcnt(" #N ")" \
        : "+v"(a),"+v"(b),"+v"(c),"+v"(d),"+v"(e),"+v"(f),"+v"(g),"+v"(h) :: "memory")
#define LSTM9_WAIT2(a,b) \
    asm volatile("s_waitcnt vmcnt(0)" : "+v"(a),"+v"(b) :: "memory")
#define LSTM9_WP16(a,b) \
    asm volatile("s_waitcnt vmcnt(16)" : "+v"(a),"+v"(b) :: "memory")
// write-through stores (no dirty L2 lines anywhere)
__device__ __forceinline__ void lstm9_stH(unsigned short* p, unsigned short v) {
    unsigned int x = v;
    asm volatile("global_store_short %0, %1, off sc0 sc1" :: "v"(p), "v"(x) : "memory");
}
__device__ __forceinline__ void lstm9_stF(float* p, float v) {
    asm volatile("global_store_dword %0, %1, off sc0 sc1" :: "v"(p), "v"(v) : "memory");
}
__device__ __forceinline__ void lstm9_stI(int* p, int v) {
    asm volatile("global_store_dword %0, %1, off sc0 sc1" :: "v"(p), "v"(v) : "memory");
}
__device__ __forceinline__ void lstm9_drain() {
    asm volatile("s_waitcnt vmcnt(0)" ::: "memory");
}
// acquire: invalidate clean L2 lines so cached loads see producer data
__device__ __forceinline__ void lstm9_acq() {
    __builtin_amdgcn_fence(__ATOMIC_ACQUIRE, "agent");
}

// ---- group barriers: bounded polls (never spin forever) ----
__device__ __forceinline__ void lstm9_waitgrp(const int* base) {
    if (threadIdx.x < 64) {
        const int sl = (int)threadIdx.x & 31;
        int tries = 0;
        for (;;) {
            int f;
            asm volatile("global_load_dword %0, %1, off sc0 sc1\n\t"
                         "s_waitcnt vmcnt(0)"
                         : "=v"(f) : "v"(base + sl) : "memory");
            if (__all(f != 0)) break;
            if (++tries > (1 << 15)) break;   // valve: absmax-visible, no hang
            __builtin_amdgcn_s_sleep(1);
        }
    }
    __syncthreads();
}
__device__ __forceinline__ void lstm9_waitgrp2(const int* baseA, const int* baseB) {
    if (threadIdx.x < 64) {
        const int sl = (int)threadIdx.x & 31;
        const int* p = ((threadIdx.x < 32) ? baseA : baseB) + sl;
        int tries = 0;
        for (;;) {
            int f;
            asm volatile("global_load_dword %0, %1, off sc0 sc1\n\t"
                         "s_waitcnt vmcnt(0)"
                         : "=v"(f) : "v"(p) : "memory");
            if (__all(f != 0)) break;
            if (++tries > (1 << 15)) break;
            __builtin_amdgcn_s_sleep(1);
        }
    }
    __syncthreads();
}

#define BFR0(gt, kk) (*(const bf16x8*)&Bsh0[gt][kk][lane][0])
#define BFR1(gt, kk) (*(const bf16x8*)&Bsh1[gt][kk][lane][0])
#define WHR(gt, kk)  (*(const bf16x8*)&whr[(gt) * 16 + (kk)])

// L0 MFMAs: A = rA1/rA2 (h1 fragments), B = Bsh0 (LDS), acc b0..b3.
#define LSTM9_L0_MFMAS()                                                          \
    do {                                                                          \
        _Pragma("unroll")                                                         \
        for (int ks = 0; ks < 8; ++ks) {                                          \
            const bf16x8 af = *(const bf16x8*)&rA1[ks];                           \
            b0 = __builtin_amdgcn_mfma_f32_16x16x32_bf16(af, BFR0(0, ks), b0, 0, 0, 0); \
            b1 = __builtin_amdgcn_mfma_f32_16x16x32_bf16(af, BFR0(1, ks), b1, 0, 0, 0); \
            b2 = __builtin_amdgcn_mfma_f32_16x16x32_bf16(af, BFR0(2, ks), b2, 0, 0, 0); \
            b3 = __builtin_amdgcn_mfma_f32_16x16x32_bf16(af, BFR0(3, ks), b3, 0, 0, 0); \
        }                                                                         \
        _Pragma("unroll")                                                         \
        for (int ks = 0; ks < 8; ++ks) {                                          \
            const bf16x8 af = *(const bf16x8*)&rA2[ks];                           \
            b0 = __builtin_amdgcn_mfma_f32_16x16x32_bf16(af, BFR0(0, 8 + ks), b0, 0, 0, 0); \
            b1 = __builtin_amdgcn_mfma_f32_16x16x32_bf16(af, BFR0(1, 8 + ks), b1, 0, 0, 0); \
            b2 = __builtin_amdgcn_mfma_f32_16x16x32_bf16(af, BFR0(2, 8 + ks), b2, 0, 0, 0); \
            b3 = __builtin_amdgcn_mfma_f32_16x16x32_bf16(af, BFR0(3, 8 + ks), b3, 0, 0, 0); \
        }                                                                         \
    } while (0)

// L0 epilogue: gates -> c1r, h1 stores (16 cols of this block)
#define LSTM9_L0_EPI(h1dst)                                                       \
    do {                                                                          \
        _Pragma("unroll")                                                         \
        for (int r = 0; r < 4; ++r) {                                             \
            const float gi = b0[r] + fmaf(xv[r], wxi, b0i);                       \
            const float gf = b1[r] + fmaf(xv[r], wxf, b0f);                       \
            const float gg = b2[r] + fmaf(xv[r], wxg, b0g);                       \
            const float go = b3[r] + fmaf(xv[r], wxo, b0o);                       \
            float cv = c1r[r];                                                    \
            cv = lstm9_sig(gf) * cv + lstm9_sig(gi) * tanhf(gg);                  \
            c1r[r] = cv;                                                          \
            lstm9_stH((h1dst) + (size_t)(mb + r) * NH + jv,                       \
                      lstm9_f2b(lstm9_sig(go) * tanhf(cv)));                      \
        }                                                                         \
    } while (0)

// ---- the persistent kernel: all 255 steps (128 TF + 127 AR) ----
__global__ __launch_bounds__(256, 1) void lstm9_persist(
    const float* __restrict__ xin, float* __restrict__ outf,
    const unsigned short* __restrict__ wb0,
    const unsigned short* __restrict__ wb1i,
    const unsigned short* __restrict__ wb1h,
    const float* __restrict__ bsum0, const float* __restrict__ bsum1,
    const float* __restrict__ wih0f, const float* __restrict__ wlinf,
    const float* __restrict__ blinf,
    unsigned short* h1a, unsigned short* h1b,
    unsigned short* h2a, unsigned short* h2b,
    float* parts, int* flags)
{
    __shared__ unsigned short Bsh0[4][16][64][8];   // w_hh0 fragments, 64KB
    __shared__ unsigned short Bsh1[4][16][64][8];   // w_ih1 fragments, 64KB
    __shared__ float redsh[64][17];
    __shared__ float ysh[64];

    const int tid  = threadIdx.x;
    const int lane = tid & 63;
    const int wv   = tid >> 6;        // 0..3 -> m-subtile (16 rows each)
    const int quad = lane >> 4;
    const int ln15 = lane & 15;
    const int bid  = blockIdx.x;
    const int jt = (bid & 7) * 4 + ((bid >> 3) & 3);  // j-tile (XCD spread, perf only)
    const int g  = bid >> 5;                          // m-group 0..7
    const int j0 = jt * 16;
    const int m0 = g * 64;
    const int rowA = m0 + wv * 16 + ln15;             // A-fragment row
    const int mb   = m0 + wv * 16 + quad * 4;         // epilogue row base
    const int jv   = j0 + ln15;

    // ---- one-time: wb0/wb1i into LDS in fragment order ----
    for (int idx = tid; idx < 4 * 16 * 64; idx += 256) {
        const int gt = idx >> 10;
        const int ks = (idx >> 6) & 15;
        const int l  = idx & 63;
        const int row = l & 15, q = l >> 4;
        const size_t go = ((size_t)(gt * NH + j0 + row)) * NH + ks * 32 + q * 8;
        *(u32x4*)&Bsh0[gt][ks][l][0] = *(const u32x4*)(wb0  + go);
        *(u32x4*)&Bsh1[gt][ks][l][0] = *(const u32x4*)(wb1i + go);
    }
    // ---- one-time: wb1h fragments into 256 VGPRs/lane ----
    u32x4 whr[64];
    #pragma unroll
    for (int gt = 0; gt < 4; ++gt) {
        #pragma unroll
        for (int ks = 0; ks < 16; ++ks)
            whr[gt * 16 + ks] = *(const u32x4*)(
                wb1h + ((size_t)(gt * NH + j0 + ln15)) * NH + ks * 32 + quad * 8);
    }
    __syncthreads();

    const float b0i = bsum0[jv],          b0f = bsum0[NH + jv];
    const float b0g = bsum0[2 * NH + jv], b0o = bsum0[3 * NH + jv];
    const float wxi = wih0f[jv],          wxf = wih0f[NH + jv];
    const float wxg = wih0f[2 * NH + jv], wxo = wih0f[3 * NH + jv];
    const float b1i = bsum1[jv],          b1f = bsum1[NH + jv];
    const float b1g = bsum1[2 * NH + jv], b1o = bsum1[3 * NH + jv];
    const float wl_ = wlinf[jv];
    const float bl_ = blinf[0];

    float c1r[4] = {0.f, 0.f, 0.f, 0.f};
    float c2r[4] = {0.f, 0.f, 0.f, 0.f};

    unsigned short* h1p[2] = { h1a, h1b };
    unsigned short* h2p[2] = { h2a, h2b };
    int* flagA = flags;                  // flagA[t]: h1(t) ready
    int* flagB = flags + 256 * 8 * 32;   // flagB[t]: h2(t)+parts(t) ready

    u32x4 rA1[8], rA2[8], rH2a[8], rH2b[8];

    // ---- prologue: h1(0) = f(x(0)) (h1(-1)=0 -> pure epilogue) ----
    {
        float xv[4];
        f32x4 b0 = {0.f, 0.f, 0.f, 0.f};
        f32x4 b1 = b0, b2 = b0, b3 = b0;
        #pragma unroll
        for (int r = 0; r < 4; ++r)
            xv[r] = xin[(size_t)(mb + r) * NT + 0];
        LSTM9_L0_EPI(h1p[1]);            // h1(0) lives in h1p[1]
        lstm9_drain();
        __syncthreads();
        if (tid == 0) lstm9_stI(flagA + (0 * 8 + g) * 32 + jt, 1);
    }

    for (int t = 0; t < 255; ++t) {
        const unsigned short* h1rd = h1p[(t + 1) & 1];   // h1(t)
        unsigned short*       h1wr = h1p[t & 1];         // h1(t+1) [TF] / h1(t) dst [AR]
        const unsigned short* h2rd = h2p[t & 1];         // h2(t-1)
        unsigned short*       h2wr = h2p[(t + 1) & 1];   // h2(t)

        if (t <= 127) {
            // ================= TF phase =================
            if (t == 0) lstm9_waitgrp(flagA + (0 * 8 + g) * 32);
            else        lstm9_waitgrp2(flagA + (t * 8 + g) * 32,
                                       flagB + ((t - 1) * 8 + g) * 32);
            lstm9_acq();                 // invalidate L2 -> cached loads fresh

            #pragma unroll
            for (int ks = 0; ks < 8; ++ks)
                lstm9_ldC(rH2a[ks], h2rd + (size_t)rowA * NH + ks * 32 + quad * 8);
            #pragma unroll
            for (int ks = 0; ks < 8; ++ks)
                lstm9_ldC(rH2b[ks], h2rd + (size_t)rowA * NH + (8 + ks) * 32 + quad * 8);
            #pragma unroll
            for (int ks = 0; ks < 8; ++ks)
                lstm9_ldC(rA1[ks], h1rd + (size_t)rowA * NH + ks * 32 + quad * 8);
            #pragma unroll
            for (int ks = 0; ks < 8; ++ks)
                lstm9_ldC(rA2[ks], h1rd + (size_t)rowA * NH + (8 + ks) * 32 + quad * 8);

            f32x4 a0 = {0.f, 0.f, 0.f, 0.f};
            f32x4 a1 = a0, a2 = a0, a3 = a0;
            LSTM9_W8(24, rH2a[0], rH2a[1], rH2a[2], rH2a[3],
                         rH2a[4], rH2a[5], rH2a[6], rH2a[7]);
            #pragma unroll
            for (int ks = 0; ks < 8; ++ks) {
                const bf16x8 af = *(const bf16x8*)&rH2a[ks];
                a0 = __builtin_amdgcn_mfma_f32_16x16x32_bf16(af, WHR(0, ks), a0, 0, 0, 0);
                a1 = __builtin_amdgcn_mfma_f32_16x16x32_bf16(af, WHR(1, ks), a1, 0, 0, 0);
                a2 = __builtin_amdgcn_mfma_f32_16x16x32_bf16(af, WHR(2, ks), a2, 0, 0, 0);
                a3 = __builtin_amdgcn_mfma_f32_16x16x32_bf16(af, WHR(3, ks), a3, 0, 0, 0);
            }
            LSTM9_W8(16, rH2b[0], rH2b[1], rH2b[2], rH2b[3],
                         rH2b[4], rH2b[5], rH2b[6], rH2b[7]);
            #pragma unroll
            for (int ks = 0; ks < 8; ++ks) {
                const bf16x8 af = *(const bf16x8*)&rH2b[ks];
                a0 = __builtin_amdgcn_mfma_f32_16x16x32_bf16(af, WHR(0, 8 + ks), a0, 0, 0, 0);
                a1 = __builtin_amdgcn_mfma_f32_16x16x32_bf16(af, WHR(1, 8 + ks), a1, 0, 0, 0);
                a2 = __builtin_amdgcn_mfma_f32_16x16x32_bf16(af, WHR(2, 8 + ks), a2, 0, 0, 0);
                a3 = __builtin_amdgcn_mfma_f32_16x16x32_bf16(af, WHR(3, 8 + ks), a3, 0, 0, 0);
            }
            LSTM9_W8(8, rA1[0], rA1[1], rA1[2], rA1[3],
                        rA1[4], rA1[5], rA1[6], rA1[7]);
            #pragma unroll
            for (int ks = 0; ks < 8; ++ks) {
                const bf16x8 af = *(const bf16x8*)&rA1[ks];
                a0 = __builtin_amdgcn_mfma_f32_16x16x32_bf16(af, BFR1(0, ks), a0, 0, 0, 0);
                a1 = __builtin_amdgcn_mfma_f32_16x16x32_bf16(af, BFR1(1, ks), a1, 0, 0, 0);
                a2 = __builtin_amdgcn_mfma_f32_16x16x32_bf16(af, BFR1(2, ks), a2, 0, 0, 0);
                a3 = __builtin_amdgcn_mfma_f32_16x16x32_bf16(af, BFR1(3, ks), a3, 0, 0, 0);
            }
            LSTM9_W8(0, rA2[0], rA2[1], rA2[2], rA2[3],
                        rA2[4], rA2[5], rA2[6], rA2[7]);
            #pragma unroll
            for (int ks = 0; ks < 8; ++ks) {
                const bf16x8 af = *(const bf16x8*)&rA2[ks];
                a0 = __builtin_amdgcn_mfma_f32_16x16x32_bf16(af, BFR1(0, 8 + ks), a0, 0, 0, 0);
                a1 = __builtin_amdgcn_mfma_f32_16x16x32_bf16(af, BFR1(1, 8 + ks), a1, 0, 0, 0);
                a2 = __builtin_amdgcn_mfma_f32_16x16x32_bf16(af, BFR1(2, 8 + ks), a2, 0, 0, 0);
                a3 = __builtin_amdgcn_mfma_f32_16x16x32_bf16(af, BFR1(3, 8 + ks), a3, 0, 0, 0);
            }

            float hv[4], cva[4];
            #pragma unroll
            for (int r = 0; r < 4; ++r) {
                const float gi = a0[r] + b1i;
                const float gf = a1[r] + b1f;
                const float gg = a2[r] + b1g;
                const float go = a3[r] + b1o;
                float cv = c2r[r];
                cv = lstm9_sig(gf) * cv + lstm9_sig(gi) * tanhf(gg);
                c2r[r] = cv;
                cva[r] = cv;
                hv[r] = lstm9_sig(go) * tanhf(cv);
                lstm9_stH(h2wr + (size_t)(mb + r) * NH + jv, lstm9_f2b(hv[r]));
            }

            f32x4 b0 = {0.f, 0.f, 0.f, 0.f};
            f32x4 b1 = b0, b2 = b0, b3 = b0;

            if (t < 127) {
                LSTM9_L0_MFMAS();            // L0(t+1), overlaps h2 store flight
                float xv[4];
                #pragma unroll
                for (int r = 0; r < 4; ++r)
                    xv[r] = xin[(size_t)(mb + r) * NT + (t + 1)];
                LSTM9_L0_EPI(h1wr);
                lstm9_drain();
                __syncthreads();
                if (tid == 0) {
                    lstm9_stI(flagB + (t * 8 + g) * 32 + jt, 1);
                    lstm9_stI(flagA + ((t + 1) * 8 + g) * 32 + jt, 1);
                }
            } else {
                // t == 127: parts(127) from CELL state (y0 quirk); no L0 here.
                #pragma unroll
                for (int r = 0; r < 4; ++r)
                    redsh[wv * 16 + quad * 4 + r][ln15] = cva[r] * wl_;
                __syncthreads();
                if (tid < 64) {
                    float s = 0.0f;
                    #pragma unroll
                    for (int j = 0; j < 16; ++j) s += redsh[tid][j];
                    lstm9_stF(parts + (size_t)(127 & 1) * NB * 32
                                    + (size_t)(m0 + tid) * 32 + jt, s);
                }
                lstm9_drain();
                __syncthreads();
                if (tid == 0) lstm9_stI(flagB + (127 * 8 + g) * 32 + jt, 1);
            }
        } else {
            // ================= AR phase (t = 128..254) =================
            lstm9_waitgrp(flagB + ((t - 1) * 8 + g) * 32);
            lstm9_acq();                 // invalidate L2 -> cached loads fresh

            // issue parts FIRST, then h2 (vmcnt(16) isolates parts)
            const float* pslot = parts + (size_t)((t - 1) & 1) * NB * 32;
            const int prow = tid >> 2, pq = tid & 3;
            u32x4 v0, v1;
            lstm9_ldC(v0, pslot + (size_t)(m0 + prow) * 32 + pq * 8);
            lstm9_ldC(v1, pslot + (size_t)(m0 + prow) * 32 + pq * 8 + 4);
            #pragma unroll
            for (int ks = 0; ks < 8; ++ks)
                lstm9_ldC(rH2a[ks], h2rd + (size_t)rowA * NH + ks * 32 + quad * 8);
            #pragma unroll
            for (int ks = 0; ks < 8; ++ks)
                lstm9_ldC(rH2b[ks], h2rd + (size_t)rowA * NH + (8 + ks) * 32 + quad * 8);

            // L0(t) MFMAs on persisted rA (h1(t-1)) — hides load flight
            f32x4 b0 = {0.f, 0.f, 0.f, 0.f};
            f32x4 b1 = b0, b2 = b0, b3 = b0;
            LSTM9_L0_MFMAS();

            // y(t-128) = bl + sum parts(t-1); publish + feed L0 epi
            LSTM9_WP16(v0, v1);
            {
                const float* f0 = (const float*)&v0;
                const float* f1 = (const float*)&v1;
                redsh[prow][pq] = f0[0] + f0[1] + f0[2] + f0[3]
                                + f1[0] + f1[1] + f1[2] + f1[3];
            }
            __syncthreads();
            if (tid < 64) {
                const float y = bl_ + redsh[tid][0] + redsh[tid][1]
                                    + redsh[tid][2] + redsh[tid][3];
                ysh[tid] = y;
                if (jt == 0)
                    outf[(size_t)(m0 + tid) * NT + (t - 128)] = y;
            }
            __syncthreads();
            float xv[4];
            #pragma unroll
            for (int r = 0; r < 4; ++r)
                xv[r] = ysh[wv * 16 + quad * 4 + r];

            // L0 epi -> h1(t) stores -> flagA(t)
            LSTM9_L0_EPI(h1wr);
            lstm9_drain();               // h1 stores acked; rH2 also complete
            __syncthreads();
            if (tid == 0) lstm9_stI(flagA + (t * 8 + g) * 32 + jt, 1);

            // h2×whr MFMAs hidden under flagA flight + skew
            f32x4 a0 = {0.f, 0.f, 0.f, 0.f};
            f32x4 a1 = a0, a2 = a0, a3 = a0;
            #pragma unroll
            for (int ks = 0; ks < 8; ++ks) {
                const bf16x8 af = *(const bf16x8*)&rH2a[ks];
                a0 = __builtin_amdgcn_mfma_f32_16x16x32_bf16(af, WHR(0, ks), a0, 0, 0, 0);
                a1 = __builtin_amdgcn_mfma_f32_16x16x32_bf16(af, WHR(1, ks), a1, 0, 0, 0);
                a2 = __builtin_amdgcn_mfma_f32_16x16x32_bf16(af, WHR(2, ks), a2, 0, 0, 0);
                a3 = __builtin_amdgcn_mfma_f32_16x16x32_bf16(af, WHR(3, ks), a3, 0, 0, 0);
            }
            #pragma unroll
            for (int ks = 0; ks < 8; ++ks) {
                const bf16x8 af = *(const bf16x8*)&rH2b[ks];
                a0 = __builtin_amdgcn_mfma_f32_16x16x32_bf16(af, WHR(0, 8 + ks), a0, 0, 0, 0);
                a1 = __builtin_amdgcn_mfma_f32_16x16x32_bf16(af, WHR(1, 8 + ks), a1, 0, 0, 0);
                a2 = __builtin_amdgcn_mfma_f32_16x16x32_bf16(af, WHR(2, 8 + ks), a2, 0, 0, 0);
                a3 = __builtin_amdgcn_mfma_f32_16x16x32_bf16(af, WHR(3, 8 + ks), a3, 0, 0, 0);
            }

            // poll flagA(t); then fresh h1(t) loads (persist into next L0)
            lstm9_waitgrp(flagA + (t * 8 + g) * 32);
            lstm9_acq();
            #pragma unroll
            for (int ks = 0; ks < 8; ++ks)
                lstm9_ldC(rA1[ks], h1wr + (size_t)rowA * NH + ks * 32 + quad * 8);
            #pragma unroll
            for (int ks = 0; ks < 8; ++ks)
                lstm9_ldC(rA2[ks], h1wr + (size_t)rowA * NH + (8 + ks) * 32 + quad * 8);
            LSTM9_W8(8, rA1[0], rA1[1], rA1[2], rA1[3],
                        rA1[4], rA1[5], rA1[6], rA1[7]);
            #pragma unroll
            for (int ks = 0; ks < 8; ++ks) {
                const bf16x8 af = *(const bf16x8*)&rA1[ks];
                a0 = __builtin_amdgcn_mfma_f32_16x16x32_bf16(af, BFR1(0, ks), a0, 0, 0, 0);
                a1 = __builtin_amdgcn_mfma_f32_16x16x32_bf16(af, BFR1(1, ks), a1, 0, 0, 0);
                a2 = __builtin_amdgcn_mfma_f32_16x16x32_bf16(af, BFR1(2, ks), a2, 0, 0, 0);
                a3 = __builtin_amdgcn_mfma_f32_16x16x32_bf16(af, BFR1(3, ks), a3, 0, 0, 0);
            }
            LSTM9_W8(0, rA2[0], rA2[1], rA2[2], rA2[3],
                        rA2[4], rA2[5], rA2[6], rA2[7]);
            #pragma unroll
            for (int ks = 0; ks < 8; ++ks) {
                const bf16x8 af = *(const bf16x8*)&rA2[ks];
                a0 = __builtin_amdgcn_mfma_f32_16x16x32_bf16(af, BFR1(0, 8 + ks), a0, 0, 0, 0);
                a1 = __builtin_amdgcn_mfma_f32_16x16x32_bf16(af, BFR1(1, 8 + ks), a1, 0, 0, 0);
                a2 = __builtin_amdgcn_mfma_f32_16x16x32_bf16(af, BFR1(2, 8 + ks), a2, 0, 0, 0);
                a3 = __builtin_amdgcn_mfma_f32_16x16x32_bf16(af, BFR1(3, 8 + ks), a3, 0, 0, 0);
            }

            // L1 epi -> h2(t) + parts(t) -> flagB(t)
            float hv[4];
            #pragma unroll
            for (int r = 0; r < 4; ++r) {
                const float gi = a0[r] + b1i;
                const float gf = a1[r] + b1f;
                const float gg = a2[r] + b1g;
                const float go = a3[r] + b1o;
                float cv = c2r[r];
                cv = lstm9_sig(gf) * cv + lstm9_sig(gi) * tanhf(gg);
                c2r[r] = cv;
                hv[r] = lstm9_sig(go) * tanhf(cv);
                lstm9_stH(h2wr + (size_t)(mb + r) * NH + jv, lstm9_f2b(hv[r]));
            }
            #pragma unroll
            for (int r = 0; r < 4; ++r)
                redsh[wv * 16 + quad * 4 + r][ln15] = hv[r] * wl_;
            __syncthreads();
            if (tid < 64) {
                float s = 0.0f;
                #pragma unroll
                for (int j = 0; j < 16; ++j) s += redsh[tid][j];
                lstm9_stF(parts + (size_t)(t & 1) * NB * 32
                                + (size_t)(m0 + tid) * 32 + jt, s);
            }
            lstm9_drain();
            __syncthreads();
            if (tid == 0) lstm9_stI(flagB + (t * 8 + g) * 32 + jt, 1);
        }
    }

    // ---- epilogue: final output column (from parts(254)) ----
    lstm9_waitgrp(flagB + (254 * 8 + g) * 32);
    lstm9_acq();
    {
        const float* pslot = parts + (size_t)(254 & 1) * NB * 32;
        const int prow = tid >> 2, pq = tid & 3;
        u32x4 v0, v1;
        lstm9_ldC(v0, pslot + (size_t)(m0 + prow) * 32 + pq * 8);
        lstm9_ldC(v1, pslot + (size_t)(m0 + prow) * 32 + pq * 8 + 4);
        LSTM9_WAIT2(v0, v1);
        const float* f0 = (const float*)&v0;
        const float* f1 = (const float*)&v1;
        redsh[prow][pq] = f0[0] + f0[1] + f0[2] + f0[3]
                        + f1[0] + f1[1] + f1[2] + f1[3];
    }
    __syncthreads();
    if (tid < 64 && jt == 0) {
        const float y = bl_ + redsh[tid][0] + redsh[tid][1]
                            + redsh[tid][2] + redsh[tid][3];
        outf[(size_t)(m0 + tid) * NT + 127] = y;
    }
}

extern "C" void kernel_launch(void* const* d_in, const int* in_sizes, int n_in,
                              void* d_out, int out_size, void* d_ws, size_t ws_size,
                              hipStream_t stream)
{
    int base = 3;
    if (!(n_in > 3 && in_sizes[3] == 4 * NH)) {
        for (int i = 1; i + 9 < n_in; ++i)
            if (in_sizes[i] == 4 * NH) { base = i; break; }
    }
    const float* xin  = (const float*)d_in[0];
    const float* wih0 = (const float*)d_in[base + 0];
    const float* whh0 = (const float*)d_in[base + 1];
    const float* bih0 = (const float*)d_in[base + 2];
    const float* bhh0 = (const float*)d_in[base + 3];
    const float* wih1 = (const float*)d_in[base + 4];
    const float* whh1 = (const float*)d_in[base + 5];
    const float* bih1 = (const float*)d_in[base + 6];
    const float* bhh1 = (const float*)d_in[base + 7];
    const float* wlin = (const float*)d_in[base + 8];
    const float* blin = (const float*)d_in[base + 9];
    float* outf = (float*)d_out;

    // ws layout (~9 MB): bf16 weights | bf16 h ping-pong | fp32 bias |
    // y-partials | flags.
    const size_t NW = (size_t)4 * NH * NH;
    const size_t S  = (size_t)NB * NH;
    unsigned short* wb0  = (unsigned short*)d_ws;
    unsigned short* wb1i = wb0 + NW;
    unsigned short* wb1h = wb1i + NW;
    unsigned short* h1b0 = wb1h + NW;
    unsigned short* h1b1 = h1b0 + S;
    unsigned short* h2b0 = h1b1 + S;
    unsigned short* h2b1 = h2b0 + S;
    float* bsum0 = (float*)(h2b1 + S);
    float* bsum1 = bsum0 + 4 * NH;
    float* parts = bsum1 + 4 * NH;               // 2 slots x 512 m x 32 j
    int*   flags = (int*)(parts + 2 * NB * 32);  // flagA | flagB

    lstm9_mark<<<(NB * NT + 255) / 256, 256, 0, stream>>>(outf);
    lstm9_prep<<<1024, 256, 0, stream>>>(whh0, wih1, whh1, bih0, bhh0, bih1, bhh1,
                                         wb0, wb1i, wb1h, bsum0, bsum1,
                                         h1b0, flags);
    lstm9_persist<<<256, 256, 0, stream>>>(xin, outf, wb0, wb1i, wb1h,
                                           bsum0, bsum1, wih0, wlin, blin,
                                           h1b0, h1b1, h2b0, h2b1,
                                           parts, flags);
}

// Round 12
// 3014.196 us; speedup vs baseline: 1.3625x; 1.3625x over previous
//
#include <hip/hip_runtime.h>
#include <math.h>
#include <stdint.h>

// ReLSTM_18940805775611 — B=512, T=128, H=512, 2-layer LSTM, 128 TF + 127 AR.
// R29 (3030us, BEST): persistent, ITER fusion, MALL-scope flag sync, AR
// restructure (one flagB poll covers h2+parts; L0 on persisted rA regs).
// R30 (4107us REGRESSION): cached h reads + acquire fences — fences cost
// ~2x their benefit; decontention theory falsified (FETCH unchanged).
// R31 = exact R29 protocol + two zero-risk trims:
//  (1) merged TF flag: flagB(t) & flagA(t+1) (always stored back-to-back,
//      always polled together) fold into ONE flagC(t) store/poll.
//      flagA keeps t=0 prologue + AR use; flagB keeps t>=127 + AR use.
//  (2) polls spin without s_sleep for the first 8 tries (detect latency is
//      RT-bound; early sleep only delays detection), then back off.
// Accumulated floor analysis: AR needs 2 MALL exchanges/step (h1; h2+parts),
// TF 1; each exchange ~2 serial RTs at ~1us-class device-scope latency +
// ~2.5us compute -> ~2.3-2.8ms structural floor for this design. R29 is
// within ~15% of that; if R31 lands >=3000us the practical ceiling is hit.

namespace {
constexpr int NH  = 512;    // hidden
constexpr int NT  = 128;    // seq len
constexpr int NB  = 512;    // batch
}

typedef __attribute__((ext_vector_type(8))) short bf16x8;
typedef __attribute__((ext_vector_type(4))) float f32x4;
typedef __attribute__((ext_vector_type(4))) unsigned int u32x4;

// Present in case the harness resolves this symbol.
__global__ void ReLSTM_18940805775611_kernel() {}

__device__ __forceinline__ unsigned short lstm9_f2b(float f) {
    union { float f; uint32_t i; } v; v.f = f;
    const uint32_t r = v.i + 0x7FFFu + ((v.i >> 16) & 1u);   // RNE
    return (unsigned short)(r >> 16);
}
__device__ __forceinline__ float lstm9_sig(float x) {
    return 1.0f / (1.0f + expf(-x));
}

// ---- sentinel: truncation diagnostic ----
__global__ void lstm9_mark(float* out) {
    const int i = blockIdx.x * blockDim.x + threadIdx.x;
    if (i < NB * NT) out[i] = 2.03125f;
}

// ---- one-time prep (re-run every launch -> graph-replay safe) ----
__global__ void lstm9_prep(
    const float* whh0, const float* wih1, const float* whh1,
    const float* bih0, const float* bhh0, const float* bih1, const float* bhh1,
    unsigned short* wb0, unsigned short* wb1i, unsigned short* wb1h,
    float* bsum0, float* bsum1,
    unsigned short* hz, int* flags)
{
    const size_t stride = (size_t)gridDim.x * blockDim.x;
    const size_t i0 = (size_t)blockIdx.x * blockDim.x + threadIdx.x;
    const size_t NW = (size_t)4 * NH * NH;
    for (size_t i = i0; i < NW; i += stride) {
        wb0 [i] = lstm9_f2b(whh0[i]);
        wb1i[i] = lstm9_f2b(wih1[i]);
        wb1h[i] = lstm9_f2b(whh1[i]);
    }
    for (size_t i = i0; i < (size_t)4 * NH; i += stride) {
        bsum0[i] = bih0[i] + bhh0[i];
        bsum1[i] = bih1[i] + bhh1[i];
    }
    for (size_t i = i0; i < (size_t)4 * NB * NH; i += stride) hz[i] = 0;
    for (size_t i = i0; i < (size_t)3 * 256 * 8 * 32; i += stride) flags[i] = 0;
}

// ---- asm memory helpers (sc0 sc1 = MALL scope, the only working sync
// scope per R28; cached reads + fences regressed per R30) ----
__device__ __forceinline__ void lstm9_ldA(u32x4& d, const void* p) {
    asm volatile("global_load_dwordx4 %0, %1, off sc0 sc1"
                 : "=v"(d) : "v"(p) : "memory");
}
#define LSTM9_W8(N, a,b,c,d,e,f,g,h) \
    asm volatile("s_waitcnt vmcnt(" #N ")" \
        : "+v"(a),"+v"(b),"+v"(c),"+v"(d),"+v"(e),"+v"(f),"+v"(g),"+v"(h) :: "memory")
#define LSTM9_WAIT2(a,b) \
    asm volatile("s_waitcnt vmcnt(0)" : "+v"(a),"+v"(b) :: "memory")
#define LSTM9_WP16(a,b) \
    asm volatile("s_waitcnt vmcnt(16)" : "+v"(a),"+v"(b) :: "memory")
__device__ __forceinline__ void lstm9_stH(unsigned short* p, unsigned short v) {
    unsigned int x = v;
    asm volatile("global_store_short %0, %1, off sc0 sc1" :: "v"(p), "v"(x) : "memory");
}
__device__ __forceinline__ void lstm9_stF(float* p, float v) {
    asm volatile("global_store_dword %0, %1, off sc0 sc1" :: "v"(p), "v"(v) : "memory");
}
__device__ __forceinline__ void lstm9_stI(int* p, int v) {
    asm volatile("global_store_dword %0, %1, off sc0 sc1" :: "v"(p), "v"(v) : "memory");
}
__device__ __forceinline__ void lstm9_drain() {
    asm volatile("s_waitcnt vmcnt(0)" ::: "memory");
}

// ---- group barrier: bounded poll, no sleep for first 8 tries ----
__device__ __forceinline__ void lstm9_waitgrp(const int* base) {
    if (threadIdx.x < 64) {
        const int sl = (int)threadIdx.x & 31;
        int tries = 0;
        for (;;) {
            int f;
            asm volatile("global_load_dword %0, %1, off sc0 sc1\n\t"
                         "s_waitcnt vmcnt(0)"
                         : "=v"(f) : "v"(base + sl) : "memory");
            if (__all(f != 0)) break;
            ++tries;
            if (tries > (1 << 15)) break;     // valve: absmax-visible, no hang
            if (tries > 8) __builtin_amdgcn_s_sleep(1);
        }
    }
    __syncthreads();
}

#define BFR0(gt, kk) (*(const bf16x8*)&Bsh0[gt][kk][lane][0])
#define BFR1(gt, kk) (*(const bf16x8*)&Bsh1[gt][kk][lane][0])
#define WHR(gt, kk)  (*(const bf16x8*)&whr[(gt) * 16 + (kk)])

// L0 MFMAs: A = rA1/rA2 (h1 fragments), B = Bsh0 (LDS), acc b0..b3.
#define LSTM9_L0_MFMAS()                                                          \
    do {                                                                          \
        _Pragma("unroll")                                                         \
        for (int ks = 0; ks < 8; ++ks) {                                          \
            const bf16x8 af = *(const bf16x8*)&rA1[ks];                           \
            b0 = __builtin_amdgcn_mfma_f32_16x16x32_bf16(af, BFR0(0, ks), b0, 0, 0, 0); \
            b1 = __builtin_amdgcn_mfma_f32_16x16x32_bf16(af, BFR0(1, ks), b1, 0, 0, 0); \
            b2 = __builtin_amdgcn_mfma_f32_16x16x32_bf16(af, BFR0(2, ks), b2, 0, 0, 0); \
            b3 = __builtin_amdgcn_mfma_f32_16x16x32_bf16(af, BFR0(3, ks), b3, 0, 0, 0); \
        }                                                                         \
        _Pragma("unroll")                                                         \
        for (int ks = 0; ks < 8; ++ks) {                                          \
            const bf16x8 af = *(const bf16x8*)&rA2[ks];                           \
            b0 = __builtin_amdgcn_mfma_f32_16x16x32_bf16(af, BFR0(0, 8 + ks), b0, 0, 0, 0); \
            b1 = __builtin_amdgcn_mfma_f32_16x16x32_bf16(af, BFR0(1, 8 + ks), b1, 0, 0, 0); \
            b2 = __builtin_amdgcn_mfma_f32_16x16x32_bf16(af, BFR0(2, 8 + ks), b2, 0, 0, 0); \
            b3 = __builtin_amdgcn_mfma_f32_16x16x32_bf16(af, BFR0(3, 8 + ks), b3, 0, 0, 0); \
        }                                                                         \
    } while (0)

// L0 epilogue: gates -> c1r, h1 stores (16 cols of this block)
#define LSTM9_L0_EPI(h1dst)                                                       \
    do {                                                                          \
        _Pragma("unroll")                                                         \
        for (int r = 0; r < 4; ++r) {                                             \
            const float gi = b0[r] + fmaf(xv[r], wxi, b0i);                       \
            const float gf = b1[r] + fmaf(xv[r], wxf, b0f);                       \
            const float gg = b2[r] + fmaf(xv[r], wxg, b0g);                       \
            const float go = b3[r] + fmaf(xv[r], wxo, b0o);                       \
            float cv = c1r[r];                                                    \
            cv = lstm9_sig(gf) * cv + lstm9_sig(gi) * tanhf(gg);                  \
            c1r[r] = cv;                                                          \
            lstm9_stH((h1dst) + (size_t)(mb + r) * NH + jv,                       \
                      lstm9_f2b(lstm9_sig(go) * tanhf(cv)));                      \
        }                                                                         \
    } while (0)

// ---- the persistent kernel: all 255 steps (128 TF + 127 AR) ----
__global__ __launch_bounds__(256, 1) void lstm9_persist(
    const float* __restrict__ xin, float* __restrict__ outf,
    const unsigned short* __restrict__ wb0,
    const unsigned short* __restrict__ wb1i,
    const unsigned short* __restrict__ wb1h,
    const float* __restrict__ bsum0, const float* __restrict__ bsum1,
    const float* __restrict__ wih0f, const float* __restrict__ wlinf,
    const float* __restrict__ blinf,
    unsigned short* h1a, unsigned short* h1b,
    unsigned short* h2a, unsigned short* h2b,
    float* parts, int* flags)
{
    __shared__ unsigned short Bsh0[4][16][64][8];   // w_hh0 fragments, 64KB
    __shared__ unsigned short Bsh1[4][16][64][8];   // w_ih1 fragments, 64KB
    __shared__ float redsh[64][17];
    __shared__ float ysh[64];

    const int tid  = threadIdx.x;
    const int lane = tid & 63;
    const int wv   = tid >> 6;        // 0..3 -> m-subtile (16 rows each)
    const int quad = lane >> 4;
    const int ln15 = lane & 15;
    const int bid  = blockIdx.x;
    const int jt = (bid & 7) * 4 + ((bid >> 3) & 3);  // j-tile (XCD spread, perf only)
    const int g  = bid >> 5;                          // m-group 0..7
    const int j0 = jt * 16;
    const int m0 = g * 64;
    const int rowA = m0 + wv * 16 + ln15;             // A-fragment row
    const int mb   = m0 + wv * 16 + quad * 4;         // epilogue row base
    const int jv   = j0 + ln15;

    // ---- one-time: wb0/wb1i into LDS in fragment order ----
    for (int idx = tid; idx < 4 * 16 * 64; idx += 256) {
        const int gt = idx >> 10;
        const int ks = (idx >> 6) & 15;
        const int l  = idx & 63;
        const int row = l & 15, q = l >> 4;
        const size_t go = ((size_t)(gt * NH + j0 + row)) * NH + ks * 32 + q * 8;
        *(u32x4*)&Bsh0[gt][ks][l][0] = *(const u32x4*)(wb0  + go);
        *(u32x4*)&Bsh1[gt][ks][l][0] = *(const u32x4*)(wb1i + go);
    }
    // ---- one-time: wb1h fragments into 256 VGPRs/lane ----
    u32x4 whr[64];
    #pragma unroll
    for (int gt = 0; gt < 4; ++gt) {
        #pragma unroll
        for (int ks = 0; ks < 16; ++ks)
            whr[gt * 16 + ks] = *(const u32x4*)(
                wb1h + ((size_t)(gt * NH + j0 + ln15)) * NH + ks * 32 + quad * 8);
    }
    __syncthreads();

    const float b0i = bsum0[jv],          b0f = bsum0[NH + jv];
    const float b0g = bsum0[2 * NH + jv], b0o = bsum0[3 * NH + jv];
    const float wxi = wih0f[jv],          wxf = wih0f[NH + jv];
    const float wxg = wih0f[2 * NH + jv], wxo = wih0f[3 * NH + jv];
    const float b1i = bsum1[jv],          b1f = bsum1[NH + jv];
    const float b1g = bsum1[2 * NH + jv], b1o = bsum1[3 * NH + jv];
    const float wl_ = wlinf[jv];
    const float bl_ = blinf[0];

    float c1r[4] = {0.f, 0.f, 0.f, 0.f};
    float c2r[4] = {0.f, 0.f, 0.f, 0.f};

    unsigned short* h1p[2] = { h1a, h1b };
    unsigned short* h2p[2] = { h2a, h2b };
    int* flagA = flags;                      // flagA[t]: h1(t) ready (prologue/AR)
    int* flagB = flagA + 256 * 8 * 32;       // flagB[t]: h2(t)+parts(t) ready (t>=127)
    int* flagC = flagB + 256 * 8 * 32;       // flagC[t]: h2(t) AND h1(t+1) ready (TF)

    u32x4 rA1[8], rA2[8], rH2a[8], rH2b[8];

    // ---- prologue: h1(0) = f(x(0)) (h1(-1)=0 -> pure epilogue) ----
    {
        float xv[4];
        f32x4 b0 = {0.f, 0.f, 0.f, 0.f};
        f32x4 b1 = b0, b2 = b0, b3 = b0;
        #pragma unroll
        for (int r = 0; r < 4; ++r)
            xv[r] = xin[(size_t)(mb + r) * NT + 0];
        LSTM9_L0_EPI(h1p[1]);            // h1(0) lives in h1p[1]
        lstm9_drain();
        __syncthreads();
        if (tid == 0) lstm9_stI(flagA + (0 * 8 + g) * 32 + jt, 1);
    }

    for (int t = 0; t < 255; ++t) {
        const unsigned short* h1rd = h1p[(t + 1) & 1];   // h1(t)
        unsigned short*       h1wr = h1p[t & 1];         // h1(t+1) [TF] / h1(t) dst [AR]
        const unsigned short* h2rd = h2p[t & 1];         // h2(t-1)
        unsigned short*       h2wr = h2p[(t + 1) & 1];   // h2(t)

        if (t <= 127) {
            // ================= TF phase =================
            // top poll: t=0 -> flagA(0); t>=1 -> flagC(t-1) covers
            // h1(t) AND h2(t-1) AND all WAR certs (one array, one RT).
            if (t == 0) lstm9_waitgrp(flagA + (0 * 8 + g) * 32);
            else        lstm9_waitgrp(flagC + ((t - 1) * 8 + g) * 32);

            #pragma unroll
            for (int ks = 0; ks < 8; ++ks)
                lstm9_ldA(rH2a[ks], h2rd + (size_t)rowA * NH + ks * 32 + quad * 8);
            #pragma unroll
            for (int ks = 0; ks < 8; ++ks)
                lstm9_ldA(rH2b[ks], h2rd + (size_t)rowA * NH + (8 + ks) * 32 + quad * 8);
            #pragma unroll
            for (int ks = 0; ks < 8; ++ks)
                lstm9_ldA(rA1[ks], h1rd + (size_t)rowA * NH + ks * 32 + quad * 8);
            #pragma unroll
            for (int ks = 0; ks < 8; ++ks)
                lstm9_ldA(rA2[ks], h1rd + (size_t)rowA * NH + (8 + ks) * 32 + quad * 8);

            f32x4 a0 = {0.f, 0.f, 0.f, 0.f};
            f32x4 a1 = a0, a2 = a0, a3 = a0;
            LSTM9_W8(24, rH2a[0], rH2a[1], rH2a[2], rH2a[3],
                         rH2a[4], rH2a[5], rH2a[6], rH2a[7]);
            #pragma unroll
            for (int ks = 0; ks < 8; ++ks) {
                const bf16x8 af = *(const bf16x8*)&rH2a[ks];
                a0 = __builtin_amdgcn_mfma_f32_16x16x32_bf16(af, WHR(0, ks), a0, 0, 0, 0);
                a1 = __builtin_amdgcn_mfma_f32_16x16x32_bf16(af, WHR(1, ks), a1, 0, 0, 0);
                a2 = __builtin_amdgcn_mfma_f32_16x16x32_bf16(af, WHR(2, ks), a2, 0, 0, 0);
                a3 = __builtin_amdgcn_mfma_f32_16x16x32_bf16(af, WHR(3, ks), a3, 0, 0, 0);
            }
            LSTM9_W8(16, rH2b[0], rH2b[1], rH2b[2], rH2b[3],
                         rH2b[4], rH2b[5], rH2b[6], rH2b[7]);
            #pragma unroll
            for (int ks = 0; ks < 8; ++ks) {
                const bf16x8 af = *(const bf16x8*)&rH2b[ks];
                a0 = __builtin_amdgcn_mfma_f32_16x16x32_bf16(af, WHR(0, 8 + ks), a0, 0, 0, 0);
                a1 = __builtin_amdgcn_mfma_f32_16x16x32_bf16(af, WHR(1, 8 + ks), a1, 0, 0, 0);
                a2 = __builtin_amdgcn_mfma_f32_16x16x32_bf16(af, WHR(2, 8 + ks), a2, 0, 0, 0);
                a3 = __builtin_amdgcn_mfma_f32_16x16x32_bf16(af, WHR(3, 8 + ks), a3, 0, 0, 0);
            }
            LSTM9_W8(8, rA1[0], rA1[1], rA1[2], rA1[3],
                        rA1[4], rA1[5], rA1[6], rA1[7]);
            #pragma unroll
            for (int ks = 0; ks < 8; ++ks) {
                const bf16x8 af = *(const bf16x8*)&rA1[ks];
                a0 = __builtin_amdgcn_mfma_f32_16x16x32_bf16(af, BFR1(0, ks), a0, 0, 0, 0);
                a1 = __builtin_amdgcn_mfma_f32_16x16x32_bf16(af, BFR1(1, ks), a1, 0, 0, 0);
                a2 = __builtin_amdgcn_mfma_f32_16x16x32_bf16(af, BFR1(2, ks), a2, 0, 0, 0);
                a3 = __builtin_amdgcn_mfma_f32_16x16x32_bf16(af, BFR1(3, ks), a3, 0, 0, 0);
            }
            LSTM9_W8(0, rA2[0], rA2[1], rA2[2], rA2[3],
                        rA2[4], rA2[5], rA2[6], rA2[7]);
            #pragma unroll
            for (int ks = 0; ks < 8; ++ks) {
                const bf16x8 af = *(const bf16x8*)&rA2[ks];
                a0 = __builtin_amdgcn_mfma_f32_16x16x32_bf16(af, BFR1(0, 8 + ks), a0, 0, 0, 0);
                a1 = __builtin_amdgcn_mfma_f32_16x16x32_bf16(af, BFR1(1, 8 + ks), a1, 0, 0, 0);
                a2 = __builtin_amdgcn_mfma_f32_16x16x32_bf16(af, BFR1(2, 8 + ks), a2, 0, 0, 0);
                a3 = __builtin_amdgcn_mfma_f32_16x16x32_bf16(af, BFR1(3, 8 + ks), a3, 0, 0, 0);
            }

            float hv[4], cva[4];
            #pragma unroll
            for (int r = 0; r < 4; ++r) {
                const float gi = a0[r] + b1i;
                const float gf = a1[r] + b1f;
                const float gg = a2[r] + b1g;
                const float go = a3[r] + b1o;
                float cv = c2r[r];
                cv = lstm9_sig(gf) * cv + lstm9_sig(gi) * tanhf(gg);
                c2r[r] = cv;
                cva[r] = cv;
                hv[r] = lstm9_sig(go) * tanhf(cv);
                lstm9_stH(h2wr + (size_t)(mb + r) * NH + jv, lstm9_f2b(hv[r]));
            }

            f32x4 b0 = {0.f, 0.f, 0.f, 0.f};
            f32x4 b1 = b0, b2 = b0, b3 = b0;

            if (t < 127) {
                LSTM9_L0_MFMAS();            // L0(t+1), overlaps h2 store flight
                float xv[4];
                #pragma unroll
                for (int r = 0; r < 4; ++r)
                    xv[r] = xin[(size_t)(mb + r) * NT + (t + 1)];
                LSTM9_L0_EPI(h1wr);
                lstm9_drain();               // h2(t) + h1(t+1) stores acked
                __syncthreads();
                if (tid == 0) lstm9_stI(flagC + (t * 8 + g) * 32 + jt, 1);
            } else {
                // t == 127: parts(127) from CELL state (y0 quirk); no L0 here.
                #pragma unroll
                for (int r = 0; r < 4; ++r)
                    redsh[wv * 16 + quad * 4 + r][ln15] = cva[r] * wl_;
                __syncthreads();
                if (tid < 64) {
                    float s = 0.0f;
                    #pragma unroll
                    for (int j = 0; j < 16; ++j) s += redsh[tid][j];
                    lstm9_stF(parts + (size_t)(127 & 1) * NB * 32
                                    + (size_t)(m0 + tid) * 32 + jt, s);
                }
                lstm9_drain();
                __syncthreads();
                if (tid == 0) lstm9_stI(flagB + (127 * 8 + g) * 32 + jt, 1);
            }
        } else {
            // ================= AR phase (t = 128..254) =================
            // 1. ONE poll covers h2(t-1) + parts(t-1) (+ full WAR cert)
            lstm9_waitgrp(flagB + ((t - 1) * 8 + g) * 32);

            // 2. issue parts FIRST, then h2 (vmcnt(16) isolates parts)
            const float* pslot = parts + (size_t)((t - 1) & 1) * NB * 32;
            const int prow = tid >> 2, pq = tid & 3;
            u32x4 v0, v1;
            lstm9_ldA(v0, pslot + (size_t)(m0 + prow) * 32 + pq * 8);
            lstm9_ldA(v1, pslot + (size_t)(m0 + prow) * 32 + pq * 8 + 4);
            #pragma unroll
            for (int ks = 0; ks < 8; ++ks)
                lstm9_ldA(rH2a[ks], h2rd + (size_t)rowA * NH + ks * 32 + quad * 8);
            #pragma unroll
            for (int ks = 0; ks < 8; ++ks)
                lstm9_ldA(rH2b[ks], h2rd + (size_t)rowA * NH + (8 + ks) * 32 + quad * 8);

            // 3. L0(t) MFMAs on persisted rA (h1(t-1)) — hides load flight
            f32x4 b0 = {0.f, 0.f, 0.f, 0.f};
            f32x4 b1 = b0, b2 = b0, b3 = b0;
            LSTM9_L0_MFMAS();

            // 4. y(t-128) = bl + sum parts(t-1); publish + feed L0 epi
            LSTM9_WP16(v0, v1);
            {
                const float* f0 = (const float*)&v0;
                const float* f1 = (const float*)&v1;
                redsh[prow][pq] = f0[0] + f0[1] + f0[2] + f0[3]
                                + f1[0] + f1[1] + f1[2] + f1[3];
            }
            __syncthreads();
            if (tid < 64) {
                const float y = bl_ + redsh[tid][0] + redsh[tid][1]
                                    + redsh[tid][2] + redsh[tid][3];
                ysh[tid] = y;
                if (jt == 0)
                    outf[(size_t)(m0 + tid) * NT + (t - 128)] = y;
            }
            __syncthreads();
            float xv[4];
            #pragma unroll
            for (int r = 0; r < 4; ++r)
                xv[r] = ysh[wv * 16 + quad * 4 + r];

            // 5. L0 epi -> h1(t) stores -> flagA(t)
            LSTM9_L0_EPI(h1wr);
            lstm9_drain();               // h1 stores acked; rH2 also complete
            __syncthreads();
            if (tid == 0) lstm9_stI(flagA + (t * 8 + g) * 32 + jt, 1);

            // h2×whr MFMAs hidden under flagA flight + skew
            f32x4 a0 = {0.f, 0.f, 0.f, 0.f};
            f32x4 a1 = a0, a2 = a0, a3 = a0;
            #pragma unroll
            for (int ks = 0; ks < 8; ++ks) {
                const bf16x8 af = *(const bf16x8*)&rH2a[ks];
                a0 = __builtin_amdgcn_mfma_f32_16x16x32_bf16(af, WHR(0, ks), a0, 0, 0, 0);
                a1 = __builtin_amdgcn_mfma_f32_16x16x32_bf16(af, WHR(1, ks), a1, 0, 0, 0);
                a2 = __builtin_amdgcn_mfma_f32_16x16x32_bf16(af, WHR(2, ks), a2, 0, 0, 0);
                a3 = __builtin_amdgcn_mfma_f32_16x16x32_bf16(af, WHR(3, ks), a3, 0, 0, 0);
            }
            #pragma unroll
            for (int ks = 0; ks < 8; ++ks) {
                const bf16x8 af = *(const bf16x8*)&rH2b[ks];
                a0 = __builtin_amdgcn_mfma_f32_16x16x32_bf16(af, WHR(0, 8 + ks), a0, 0, 0, 0);
                a1 = __builtin_amdgcn_mfma_f32_16x16x32_bf16(af, WHR(1, 8 + ks), a1, 0, 0, 0);
                a2 = __builtin_amdgcn_mfma_f32_16x16x32_bf16(af, WHR(2, 8 + ks), a2, 0, 0, 0);
                a3 = __builtin_amdgcn_mfma_f32_16x16x32_bf16(af, WHR(3, 8 + ks), a3, 0, 0, 0);
            }

            // 6. poll flagA(t); 7. h1(t) loads (persist into next iter's L0)
            lstm9_waitgrp(flagA + (t * 8 + g) * 32);
            #pragma unroll
            for (int ks = 0; ks < 8; ++ks)
                lstm9_ldA(rA1[ks], h1wr + (size_t)rowA * NH + ks * 32 + quad * 8);
            #pragma unroll
            for (int ks = 0; ks < 8; ++ks)
                lstm9_ldA(rA2[ks], h1wr + (size_t)rowA * NH + (8 + ks) * 32 + quad * 8);
            LSTM9_W8(8, rA1[0], rA1[1], rA1[2], rA1[3],
                        rA1[4], rA1[5], rA1[6], rA1[7]);
            #pragma unroll
            for (int ks = 0; ks < 8; ++ks) {
                const bf16x8 af = *(const bf16x8*)&rA1[ks];
                a0 = __builtin_amdgcn_mfma_f32_16x16x32_bf16(af, BFR1(0, ks), a0, 0, 0, 0);
                a1 = __builtin_amdgcn_mfma_f32_16x16x32_bf16(af, BFR1(1, ks), a1, 0, 0, 0);
                a2 = __builtin_amdgcn_mfma_f32_16x16x32_bf16(af, BFR1(2, ks), a2, 0, 0, 0);
                a3 = __builtin_amdgcn_mfma_f32_16x16x32_bf16(af, BFR1(3, ks), a3, 0, 0, 0);
            }
            LSTM9_W8(0, rA2[0], rA2[1], rA2[2], rA2[3],
                        rA2[4], rA2[5], rA2[6], rA2[7]);
            #pragma unroll
            for (int ks = 0; ks < 8; ++ks) {
                const bf16x8 af = *(const bf16x8*)&rA2[ks];
                a0 = __builtin_amdgcn_mfma_f32_16x16x32_bf16(af, BFR1(0, 8 + ks), a0, 0, 0, 0);
                a1 = __builtin_amdgcn_mfma_f32_16x16x32_bf16(af, BFR1(1, 8 + ks), a1, 0, 0, 0);
                a2 = __builtin_amdgcn_mfma_f32_16x16x32_bf16(af, BFR1(2, 8 + ks), a2, 0, 0, 0);
                a3 = __builtin_amdgcn_mfma_f32_16x16x32_bf16(af, BFR1(3, 8 + ks), a3, 0, 0, 0);
            }

            // 8. L1 epi -> h2(t) + parts(t) -> flagB(t)
            float hv[4];
            #pragma unroll
            for (int r = 0; r < 4; ++r) {
                const float gi = a0[r] + b1i;
                const float gf = a1[r] + b1f;
                const float gg = a2[r] + b1g;
                const float go = a3[r] + b1o;
                float cv = c2r[r];
                cv = lstm9_sig(gf) * cv + lstm9_sig(gi) * tanhf(gg);
                c2r[r] = cv;
                hv[r] = lstm9_sig(go) * tanhf(cv);
                lstm9_stH(h2wr + (size_t)(mb + r) * NH + jv, lstm9_f2b(hv[r]));
            }
            #pragma unroll
            for (int r = 0; r < 4; ++r)
                redsh[wv * 16 + quad * 4 + r][ln15] = hv[r] * wl_;
            __syncthreads();
            if (tid < 64) {
                float s = 0.0f;
                #pragma unroll
                for (int j = 0; j < 16; ++j) s += redsh[tid][j];
                lstm9_stF(parts + (size_t)(t & 1) * NB * 32
                                + (size_t)(m0 + tid) * 32 + jt, s);
            }
            lstm9_drain();
            __syncthreads();
            if (tid == 0) lstm9_stI(flagB + (t * 8 + g) * 32 + jt, 1);
        }
    }

    // ---- epilogue: final output column (from parts(254)) ----
    lstm9_waitgrp(flagB + (254 * 8 + g) * 32);
    {
        const float* pslot = parts + (size_t)(254 & 1) * NB * 32;
        const int prow = tid >> 2, pq = tid & 3;
        u32x4 v0, v1;
        lstm9_ldA(v0, pslot + (size_t)(m0 + prow) * 32 + pq * 8);
        lstm9_ldA(v1, pslot + (size_t)(m0 + prow) * 32 + pq * 8 + 4);
        LSTM9_WAIT2(v0, v1);
        const float* f0 = (const float*)&v0;
        const float* f1 = (const float*)&v1;
        redsh[prow][pq] = f0[0] + f0[1] + f0[2] + f0[3]
                        + f1[0] + f1[1] + f1[2] + f1[3];
    }
    __syncthreads();
    if (tid < 64 && jt == 0) {
        const float y = bl_ + redsh[tid][0] + redsh[tid][1]
                            + redsh[tid][2] + redsh[tid][3];
        outf[(size_t)(m0 + tid) * NT + 127] = y;
    }
}

extern "C" void kernel_launch(void* const* d_in, const int* in_sizes, int n_in,
                              void* d_out, int out_size, void* d_ws, size_t ws_size,
                              hipStream_t stream)
{
    int base = 3;
    if (!(n_in > 3 && in_sizes[3] == 4 * NH)) {
        for (int i = 1; i + 9 < n_in; ++i)
            if (in_sizes[i] == 4 * NH) { base = i; break; }
    }
    const float* xin  = (const float*)d_in[0];
    const float* wih0 = (const float*)d_in[base + 0];
    const float* whh0 = (const float*)d_in[base + 1];
    const float* bih0 = (const float*)d_in[base + 2];
    const float* bhh0 = (const float*)d_in[base + 3];
    const float* wih1 = (const float*)d_in[base + 4];
    const float* whh1 = (const float*)d_in[base + 5];
    const float* bih1 = (const float*)d_in[base + 6];
    const float* bhh1 = (const float*)d_in[base + 7];
    const float* wlin = (const float*)d_in[base + 8];
    const float* blin = (const float*)d_in[base + 9];
    float* outf = (float*)d_out;

    // ws layout (~9.3 MB): bf16 weights | bf16 h ping-pong | fp32 bias |
    // y-partials | flags (A|B|C).
    const size_t NW = (size_t)4 * NH * NH;
    const size_t S  = (size_t)NB * NH;
    unsigned short* wb0  = (unsigned short*)d_ws;
    unsigned short* wb1i = wb0 + NW;
    unsigned short* wb1h = wb1i + NW;
    unsigned short* h1b0 = wb1h + NW;
    unsigned short* h1b1 = h1b0 + S;
    unsigned short* h2b0 = h1b1 + S;
    unsigned short* h2b1 = h2b0 + S;
    float* bsum0 = (float*)(h2b1 + S);
    float* bsum1 = bsum0 + 4 * NH;
    float* parts = bsum1 + 4 * NH;               // 2 slots x 512 m x 32 j
    int*   flags = (int*)(parts + 2 * NB * 32);  // flagA | flagB | flagC

    lstm9_mark<<<(NB * NT + 255) / 256, 256, 0, stream>>>(outf);
    lstm9_prep<<<1024, 256, 0, stream>>>(whh0, wih1, whh1, bih0, bhh0, bih1, bhh1,
                                         wb0, wb1i, wb1h, bsum0, bsum1,
                                         h1b0, flags);
    lstm9_persist<<<256, 256, 0, stream>>>(xin, outf, wb0, wb1i, wb1h,
                                           bsum0, bsum1, wih0, wlin, blin,
                                           h1b0, h1b1, h2b0, h2b1,
                                           parts, flags);
}